// Round 1
// baseline (788.951 us; speedup 1.0000x reference)
//
#include <hip/hip_runtime.h>
#include <hip/hip_bf16.h>

typedef __attribute__((ext_vector_type(8))) __bf16 bf16x8;
typedef __attribute__((ext_vector_type(4))) __bf16 bf16x4;
typedef __attribute__((ext_vector_type(4))) float  f32x4;

#define DIM   2304
#define MR    8192
#define NH    24
#define HD    96
#define SPS   512

// ---- async global->LDS, 16B per lane (dest = wave-uniform base + lane*16) ----
__device__ __forceinline__ void gload16(const void* gp, void* lp) {
  __builtin_amdgcn_global_load_lds(
      (__attribute__((address_space(1))) void*)(unsigned long long)gp,
      (__attribute__((address_space(3))) void*)lp, 16, 0, 0);
}

// ---- weight transpose + bf16 cast: dst[n][k] = (bf16) src[k][n] ----
__global__ __launch_bounds__(256) void pack_w_kernel(
    const float* __restrict__ wq, const float* __restrict__ wk,
    const float* __restrict__ wv, const float* __restrict__ wo,
    __bf16* __restrict__ dqkv, __bf16* __restrict__ dwo)
{
  __shared__ float t[64][65];
  const int z = blockIdx.z;
  const float* src = (z == 0) ? wq : (z == 1) ? wk : (z == 2) ? wv : wo;
  __bf16* dst = (z < 3) ? (dqkv + (size_t)z * DIM * DIM) : dwo;
  const int n0 = blockIdx.x * 64, k0 = blockIdx.y * 64;
  const int tx = threadIdx.x & 63, ty = threadIdx.x >> 6;
#pragma unroll
  for (int j = 0; j < 64; j += 4)
    t[ty + j][tx] = src[(size_t)(k0 + ty + j) * DIM + n0 + tx];
  __syncthreads();
#pragma unroll
  for (int j = 0; j < 64; j += 4)
    dst[(size_t)(n0 + ty + j) * DIM + k0 + tx] = (__bf16)t[tx][ty + j];
}

// ---- hidden_states fp32 -> bf16 ----
__global__ __launch_bounds__(256) void pack_hs_kernel(
    const float4* __restrict__ src, bf16x4* __restrict__ dst)
{
  const int i = blockIdx.x * 256 + threadIdx.x;
  const float4 f = src[i];
  bf16x4 o = { (__bf16)f.x, (__bf16)f.y, (__bf16)f.z, (__bf16)f.w };
  dst[i] = o;
}

// ---- fused QKV GEMM: [8192x2304] x [6912x2304]^T, epilogue scatters to
//      attention layout [b'(16)][h(24)][g(512)][d(96)] per matrix ----
__global__ __launch_bounds__(256) void gemm_qkv_kernel(
    const __bf16* __restrict__ A, const __bf16* __restrict__ B,
    const float* __restrict__ bq, const float* __restrict__ bk, const float* __restrict__ bv,
    __bf16* __restrict__ oq, __bf16* __restrict__ ok, __bf16* __restrict__ ov)
{
  __shared__ __bf16 As[128 * 64];
  __shared__ __bf16 Bs[128 * 64];
  const int tid = threadIdx.x;
  const int w = tid >> 6, l = tid & 63;
  const int lq = l & 15, lg = l >> 4;
  const int m0 = blockIdx.y * 128, n0 = blockIdx.x * 128;
  const int wm = w >> 1, wn = w & 1;
  const int arow = l >> 3, acol = (l & 7) * 8;
  f32x4 acc[4][4] = {};
  for (int k0 = 0; k0 < DIM; k0 += 64) {
#pragma unroll
    for (int p = 0; p < 4; ++p) {
      const int row = p * 32 + w * 8;
      gload16(A + (size_t)(m0 + row + arow) * DIM + k0 + acol, &As[row * 64]);
      gload16(B + (size_t)(n0 + row + arow) * DIM + k0 + acol, &Bs[row * 64]);
    }
    asm volatile("s_waitcnt vmcnt(0)" ::: "memory");
    __syncthreads();
#pragma unroll
    for (int kk = 0; kk < 2; ++kk) {
      bf16x8 af[4], bfr[4];
#pragma unroll
      for (int i = 0; i < 4; ++i)
        af[i] = *(const bf16x8*)&As[(wm * 64 + i * 16 + lq) * 64 + kk * 32 + lg * 8];
#pragma unroll
      for (int j = 0; j < 4; ++j)
        bfr[j] = *(const bf16x8*)&Bs[(wn * 64 + j * 16 + lq) * 64 + kk * 32 + lg * 8];
#pragma unroll
      for (int i = 0; i < 4; ++i)
#pragma unroll
        for (int j = 0; j < 4; ++j)
          acc[i][j] = __builtin_amdgcn_mfma_f32_16x16x32_bf16(af[i], bfr[j], acc[i][j], 0, 0, 0);
    }
    __syncthreads();
  }
  const int mat = n0 / DIM;
  const float* bias = (mat == 0) ? bq : (mat == 1) ? bk : bv;
  __bf16* outp = (mat == 0) ? oq : (mat == 1) ? ok : ov;
  const int nb = n0 - mat * DIM;
#pragma unroll
  for (int i = 0; i < 4; ++i) {
    const int gq = (m0 + wm * 64 + i * 16) >> 4;   // sparse row g (fixed per 16-row tile)
#pragma unroll
    for (int j = 0; j < 4; ++j) {
      const int n = nb + wn * 64 + j * 16 + lq;
      const int h = n / HD, d = n - (n / HD) * HD;  // 16-col runs never cross a head boundary
      const float bia = bias[n];
#pragma unroll
      for (int r = 0; r < 4; ++r) {
        const int bp = lg * 4 + r;                  // b' = row % 16
        outp[((size_t)(bp * NH + h) * SPS + gq) * HD + d] = (__bf16)(acc[i][j][r] + bia);
      }
    }
  }
}

// ---- 3D RoPE on q,k in attention layout; LDS cos/sin tables ----
__global__ __launch_bounds__(256) void rope_kernel(__bf16* __restrict__ q, __bf16* __restrict__ k)
{
  __shared__ float tc[640], ts_[640];
  const int tid = threadIdx.x;
  for (int i = tid; i < 640; i += 256) {
    int pos, jj = i & 15;
    if (i < 128)      pos = i >> 4;          // t axis: 8 pos
    else if (i < 384) pos = (i - 128) >> 4;  // h axis: 16 pos
    else              pos = (i - 384) >> 4;  // w axis: 16 pos
    const float invf = exp2f(-(float)jj * 0.83048202372184059f); // 10000^(-jj/16)
    float s, c;
    sincosf((float)pos * invf, &s, &c);
    tc[i] = c; ts_[i] = s;
  }
  __syncthreads();
  const int id = blockIdx.x * 256 + tid;       // [0, 2*16*24*512*3)
  const int cix = id % 3;
  int rest = id / 3;
  const int g = rest & 511; rest >>= 9;
  const int h = rest % 24;  rest /= 24;
  const int bp = rest & 15;
  const int tensor = rest >> 4;
  __bf16* base = (tensor ? k : q) + (((size_t)(bp * NH + h) * SPS + g) * HD + cix * 32);
  const int si = g * 4 + (bp >> 2);            // original sequence position
  const int pos = (cix == 0) ? (si >> 8) : (cix == 1) ? ((si >> 4) & 15) : (si & 15);
  const int toff = ((cix == 0) ? 0 : (cix == 1) ? 128 : 384) + pos * 16;
  bf16x8 e0 = *(const bf16x8*)(base);
  bf16x8 e1 = *(const bf16x8*)(base + 8);
  bf16x8 e2 = *(const bf16x8*)(base + 16);
  bf16x8 e3 = *(const bf16x8*)(base + 24);
  bf16x8 o0, o1, o2, o3;
#pragma unroll
  for (int j = 0; j < 8; ++j) {
    float c = tc[toff + j], s = ts_[toff + j];
    float x1 = (float)e0[j], x2 = (float)e2[j];
    o0[j] = (__bf16)(x1 * c - x2 * s);
    o2[j] = (__bf16)(x2 * c + x1 * s);
    c = tc[toff + 8 + j]; s = ts_[toff + 8 + j];
    x1 = (float)e1[j]; x2 = (float)e3[j];
    o1[j] = (__bf16)(x1 * c - x2 * s);
    o3[j] = (__bf16)(x2 * c + x1 * s);
  }
  *(bf16x8*)(base)      = o0;
  *(bf16x8*)(base + 8)  = o1;
  *(bf16x8*)(base + 16) = o2;
  *(bf16x8*)(base + 24) = o3;
}

// ---- flash attention: block = (qtile 64, h, b'); 4 waves x 16 q-rows ----
__global__ __launch_bounds__(256) void attn_kernel(
    const __bf16* __restrict__ q, const __bf16* __restrict__ k,
    const __bf16* __restrict__ v, __bf16* __restrict__ ao)
{
  __shared__ __bf16 Vt[96 * 72];        // V^T tile [d][key], padded rows
  __shared__ __bf16 Pl[4][16 * 72];     // per-wave P [q][key], padded rows
  const int tid = threadIdx.x;
  const int w = tid >> 6, l = tid & 63;
  const int lq = l & 15, lg = l >> 4;
  const int qt = blockIdx.x, h = blockIdx.y, bp = blockIdx.z;
  const size_t bh = ((size_t)bp * NH + h) * SPS;
  const __bf16* qb = q + bh * HD;
  const __bf16* kb = k + bh * HD;
  const __bf16* vb = v + bh * HD;
  bf16x8 qf[3];
  {
    const __bf16* qr = qb + (size_t)(qt * 64 + w * 16 + lq) * HD + lg * 8;
    qf[0] = *(const bf16x8*)(qr);
    qf[1] = *(const bf16x8*)(qr + 32);
    qf[2] = *(const bf16x8*)(qr + 64);
  }
  const float sc = 0.10206207261596575f * 1.4426950408889634f; // 96^-0.5 * log2(e)
  float m_run = -1e30f, l_run = 0.f;
  f32x4 o[6] = {};
  for (int kb0 = 0; kb0 < SPS; kb0 += 64) {
    __syncthreads();                     // previous PV reads of Vt done
#pragma unroll
    for (int p = 0; p < 3; ++p) {        // cooperative V^T staging
      const int lin = p * 256 + tid;
      const int row = lin / 12, c8 = (lin % 12) * 8;
      bf16x8 vv = *(const bf16x8*)(vb + (size_t)(kb0 + row) * HD + c8);
#pragma unroll
      for (int j = 0; j < 8; ++j) Vt[(c8 + j) * 72 + row] = vv[j];
    }
    __syncthreads();
    // S^T = K * Q^T  (rows=key, cols=q)  -> lane owns col q = lq
    f32x4 st[4];
#pragma unroll
    for (int t2 = 0; t2 < 4; ++t2) {
      const __bf16* kr = kb + (size_t)(kb0 + t2 * 16 + lq) * HD + lg * 8;
      bf16x8 k0f = *(const bf16x8*)(kr);
      bf16x8 k1f = *(const bf16x8*)(kr + 32);
      bf16x8 k2f = *(const bf16x8*)(kr + 64);
      f32x4 s = {};
      s = __builtin_amdgcn_mfma_f32_16x16x32_bf16(k0f, qf[0], s, 0, 0, 0);
      s = __builtin_amdgcn_mfma_f32_16x16x32_bf16(k1f, qf[1], s, 0, 0, 0);
      s = __builtin_amdgcn_mfma_f32_16x16x32_bf16(k2f, qf[2], s, 0, 0, 0);
      st[t2] = s;
    }
    // online softmax over this 64-key tile (per q = lq; keys split over lane groups)
    float tmax = -1e30f;
#pragma unroll
    for (int t2 = 0; t2 < 4; ++t2)
#pragma unroll
      for (int r = 0; r < 4; ++r) tmax = fmaxf(tmax, st[t2][r]);
    tmax = fmaxf(tmax, __shfl_xor(tmax, 16));
    tmax = fmaxf(tmax, __shfl_xor(tmax, 32));
    tmax *= sc;
    const float m_new = fmaxf(m_run, tmax);
    const float alpha = exp2f(m_run - m_new);
    float tsum = 0.f;
#pragma unroll
    for (int t2 = 0; t2 < 4; ++t2) {
      bf16x4 pb;
#pragma unroll
      for (int r = 0; r < 4; ++r) {
        const float p = exp2f(st[t2][r] * sc - m_new);
        tsum += p;
        pb[r] = (__bf16)p;
      }
      *(bf16x4*)&Pl[w][lq * 72 + t2 * 16 + lg * 4] = pb;  // P[q][key]
    }
    tsum += __shfl_xor(tsum, 16);
    tsum += __shfl_xor(tsum, 32);
    l_run = l_run * alpha + tsum;
    m_run = m_new;
    float al[4];
#pragma unroll
    for (int r = 0; r < 4; ++r) al[r] = __shfl(alpha, lg * 4 + r); // alpha for O-row q
#pragma unroll
    for (int ni = 0; ni < 6; ++ni)
#pragma unroll
      for (int r = 0; r < 4; ++r) o[ni][r] *= al[r];
    // O += P * V
#pragma unroll
    for (int ks = 0; ks < 2; ++ks) {
      bf16x8 pa = *(const bf16x8*)&Pl[w][lq * 72 + ks * 32 + lg * 8];
#pragma unroll
      for (int ni = 0; ni < 6; ++ni) {
        bf16x8 vf = *(const bf16x8*)&Vt[(ni * 16 + lq) * 72 + ks * 32 + lg * 8];
        o[ni] = __builtin_amdgcn_mfma_f32_16x16x32_bf16(pa, vf, o[ni], 0, 0, 0);
      }
    }
  }
  float linv[4];
#pragma unroll
  for (int r = 0; r < 4; ++r) linv[r] = 1.f / __shfl(l_run, lg * 4 + r);
#pragma unroll
  for (int ni = 0; ni < 6; ++ni)
#pragma unroll
    for (int r = 0; r < 4; ++r) {
      const int gq = qt * 64 + w * 16 + lg * 4 + r;
      const int d = ni * 16 + lq;
      ao[(size_t)(gq * 16 + bp) * DIM + h * HD + d] = (__bf16)(o[ni][r] * linv[r]);
    }
}

// ---- output GEMM: [8192x2304] x woT[2304x2304], fp32 out + bias ----
__global__ __launch_bounds__(256) void gemm_out_kernel(
    const __bf16* __restrict__ A, const __bf16* __restrict__ B,
    const float* __restrict__ bo, float* __restrict__ out)
{
  __shared__ __bf16 As[128 * 64];
  __shared__ __bf16 Bs[128 * 64];
  const int tid = threadIdx.x;
  const int w = tid >> 6, l = tid & 63;
  const int lq = l & 15, lg = l >> 4;
  const int m0 = blockIdx.y * 128, n0 = blockIdx.x * 128;
  const int wm = w >> 1, wn = w & 1;
  const int arow = l >> 3, acol = (l & 7) * 8;
  f32x4 acc[4][4] = {};
  for (int k0 = 0; k0 < DIM; k0 += 64) {
#pragma unroll
    for (int p = 0; p < 4; ++p) {
      const int row = p * 32 + w * 8;
      gload16(A + (size_t)(m0 + row + arow) * DIM + k0 + acol, &As[row * 64]);
      gload16(B + (size_t)(n0 + row + arow) * DIM + k0 + acol, &Bs[row * 64]);
    }
    asm volatile("s_waitcnt vmcnt(0)" ::: "memory");
    __syncthreads();
#pragma unroll
    for (int kk = 0; kk < 2; ++kk) {
      bf16x8 af[4], bfr[4];
#pragma unroll
      for (int i = 0; i < 4; ++i)
        af[i] = *(const bf16x8*)&As[(wm * 64 + i * 16 + lq) * 64 + kk * 32 + lg * 8];
#pragma unroll
      for (int j = 0; j < 4; ++j)
        bfr[j] = *(const bf16x8*)&Bs[(wn * 64 + j * 16 + lq) * 64 + kk * 32 + lg * 8];
#pragma unroll
      for (int i = 0; i < 4; ++i)
#pragma unroll
        for (int j = 0; j < 4; ++j)
          acc[i][j] = __builtin_amdgcn_mfma_f32_16x16x32_bf16(af[i], bfr[j], acc[i][j], 0, 0, 0);
    }
    __syncthreads();
  }
#pragma unroll
  for (int i = 0; i < 4; ++i) {
    const int rbase = m0 + wm * 64 + i * 16;
#pragma unroll
    for (int j = 0; j < 4; ++j) {
      const int n = n0 + wn * 64 + j * 16 + lq;
      const float bia = bo[n];
#pragma unroll
      for (int r = 0; r < 4; ++r)
        out[(size_t)(rbase + lg * 4 + r) * DIM + n] = acc[i][j][r] + bia;
    }
  }
}

extern "C" void kernel_launch(void* const* d_in, const int* in_sizes, int n_in,
                              void* d_out, int out_size, void* d_ws, size_t ws_size,
                              hipStream_t stream) {
  const float* hs = (const float*)d_in[0];
  const float* wq = (const float*)d_in[1];
  const float* bq = (const float*)d_in[2];
  const float* wk = (const float*)d_in[3];
  const float* bk = (const float*)d_in[4];
  const float* wv = (const float*)d_in[5];
  const float* bv = (const float*)d_in[6];
  const float* wo = (const float*)d_in[7];
  const float* bo = (const float*)d_in[8];
  float* out = (float*)d_out;

  char* ws = (char*)d_ws;
  // workspace layout (bytes); total 193,462,272
  __bf16* wqkvT = (__bf16*)(ws);                               // 6912*2304*2 = 31,850,496
  __bf16* woT   = (__bf16*)(ws + 31850496);                    // 2304*2304*2 = 10,616,832
  __bf16* hsb   = (__bf16*)(ws + 42467328);                    // 8192*2304*2 = 37,748,736
  __bf16* qb    = (__bf16*)(ws + 80216064);                    // 37,748,736
  __bf16* kbuf  = (__bf16*)(ws + 117964800);                   // 37,748,736
  __bf16* vbuf  = (__bf16*)(ws + 155713536);                   // 37,748,736
  __bf16* ao    = hsb;  // reuse: hs_bf16 dead after gemm_qkv

  pack_w_kernel<<<dim3(36, 36, 4), 256, 0, stream>>>(wq, wk, wv, wo, wqkvT, woT);
  pack_hs_kernel<<<18432, 256, 0, stream>>>((const float4*)hs, (bf16x4*)hsb);
  gemm_qkv_kernel<<<dim3(54, 64), 256, 0, stream>>>(hsb, wqkvT, bq, bk, bv, qb, kbuf, vbuf);
  rope_kernel<<<4608, 256, 0, stream>>>(qb, kbuf);
  attn_kernel<<<dim3(8, NH, 16), 256, 0, stream>>>(qb, kbuf, vbuf, ao);
  gemm_out_kernel<<<dim3(18, 64), 256, 0, stream>>>(ao, woT, bo, out);
}

// Round 2
// 691.069 us; speedup vs baseline: 1.1416x; 1.1416x over previous
//
#include <hip/hip_runtime.h>
#include <hip/hip_bf16.h>

typedef __attribute__((ext_vector_type(8))) __bf16 bf16x8;
typedef __attribute__((ext_vector_type(4))) __bf16 bf16x4;
typedef __attribute__((ext_vector_type(4))) float  f32x4;

#define DIM   2304
#define NH    24
#define HD    96
#define SPS   512

// ---- async global->LDS, 16B per lane (dest = wave-uniform base + lane*16) ----
__device__ __forceinline__ void gload16(const void* gp, void* lp) {
  __builtin_amdgcn_global_load_lds(
      (__attribute__((address_space(1))) void*)(unsigned long long)gp,
      (__attribute__((address_space(3))) void*)lp, 16, 0, 0);
}

// ---- weight transpose + bf16 cast: dst[n][k] = (bf16) src[k][n] ----
__global__ __launch_bounds__(256) void pack_w_kernel(
    const float* __restrict__ wq, const float* __restrict__ wk,
    const float* __restrict__ wv, const float* __restrict__ wo,
    __bf16* __restrict__ dqkv, __bf16* __restrict__ dwo)
{
  __shared__ float t[64][65];
  const int z = blockIdx.z;
  const float* src = (z == 0) ? wq : (z == 1) ? wk : (z == 2) ? wv : wo;
  __bf16* dst = (z < 3) ? (dqkv + (size_t)z * DIM * DIM) : dwo;
  const int n0 = blockIdx.x * 64, k0 = blockIdx.y * 64;
  const int tx = threadIdx.x & 63, ty = threadIdx.x >> 6;
#pragma unroll
  for (int j = 0; j < 64; j += 4)
    t[ty + j][tx] = src[(size_t)(k0 + ty + j) * DIM + n0 + tx];
  __syncthreads();
#pragma unroll
  for (int j = 0; j < 64; j += 4)
    dst[(size_t)(n0 + ty + j) * DIM + k0 + tx] = (__bf16)t[tx][ty + j];
}

// ---- hidden_states fp32 -> bf16 ----
__global__ __launch_bounds__(256) void pack_hs_kernel(
    const float4* __restrict__ src, bf16x4* __restrict__ dst)
{
  const int i = blockIdx.x * 256 + threadIdx.x;
  const float4 f = src[i];
  bf16x4 o = { (__bf16)f.x, (__bf16)f.y, (__bf16)f.z, (__bf16)f.w };
  dst[i] = o;
}

// ================= 256x256 8-phase GEMM (T1+T2+T3/T4+T5) =================
// A [M][K] row-major bf16, B [N][K] row-major bf16 (i.e. B^T of math B).
// 512 thr = 8 waves (2M x 4N), per-wave out 128x64, BK=64, LDS 128KB dbuf.
// LDS tiles XOR-swizzled: byte_col ^= (row&7)<<4; global source pre-swizzled
// (global_load_lds dest must be linear), ds_read applies same XOR.

__device__ __forceinline__ void stage_tile(
    const __bf16* __restrict__ A, const __bf16* __restrict__ B,
    __bf16* lA, __bf16* lB, int m0, int n0, int k0,
    int srow, int schunk, int dslot)
{
#pragma unroll
  for (int j = 0; j < 4; ++j)
    gload16(A + (size_t)(m0 + j * 64 + srow) * DIM + k0 + schunk,
            lA + (j * 64 + srow) * 64 + dslot);
#pragma unroll
  for (int j = 0; j < 4; ++j)
    gload16(B + (size_t)(n0 + j * 64 + srow) * DIM + k0 + schunk,
            lB + (j * 64 + srow) * 64 + dslot);
}

template<int H, int Q, bool LA, bool LB>
__device__ __forceinline__ void phase8(
    const char* ab, const char* bb, int wm, int wn, int laneA0, int laneA1,
    bf16x8 (&a)[4][2], bf16x8 (&bq)[2][2][2], f32x4 (&acc)[8][4])
{
  if (LA) {
#pragma unroll
    for (int fm = 0; fm < 4; ++fm) {
      a[fm][0] = *(const bf16x8*)(ab + (wm * 128 + H * 64 + fm * 16) * 128 + laneA0);
      a[fm][1] = *(const bf16x8*)(ab + (wm * 128 + H * 64 + fm * 16) * 128 + laneA1);
    }
  }
  if (LB) {
#pragma unroll
    for (int fn = 0; fn < 2; ++fn) {
      bq[Q][fn][0] = *(const bf16x8*)(bb + (wn * 64 + Q * 32 + fn * 16) * 128 + laneA0);
      bq[Q][fn][1] = *(const bf16x8*)(bb + (wn * 64 + Q * 32 + fn * 16) * 128 + laneA1);
    }
  }
  __builtin_amdgcn_s_barrier();
  asm volatile("s_waitcnt lgkmcnt(0)" ::: "memory");
  __builtin_amdgcn_s_setprio(1);
#pragma unroll
  for (int fm = 0; fm < 4; ++fm)
#pragma unroll
    for (int fn = 0; fn < 2; ++fn)
#pragma unroll
      for (int kk = 0; kk < 2; ++kk)
        acc[H * 4 + fm][Q * 2 + fn] = __builtin_amdgcn_mfma_f32_16x16x32_bf16(
            a[fm][kk], bq[Q][fn][kk], acc[H * 4 + fm][Q * 2 + fn], 0, 0, 0);
  __builtin_amdgcn_s_setprio(0);
  __builtin_amdgcn_s_barrier();
}

// EPI 0: fused-QKV scatter epilogue (bf16 -> attention layout). EPI 1: fp32 C.
template<int EPI>
__global__ __launch_bounds__(512, 2) void gemm8p_kernel(
    const __bf16* __restrict__ A, const __bf16* __restrict__ B,
    const float* __restrict__ b0, const float* __restrict__ b1, const float* __restrict__ b2,
    __bf16* __restrict__ o0, __bf16* __restrict__ o1, __bf16* __restrict__ o2,
    float* __restrict__ fout)
{
  __shared__ __align__(16) __bf16 As[2][256 * 64];
  __shared__ __align__(16) __bf16 Bs[2][256 * 64];
  const int tid = threadIdx.x;
  const int wid = tid >> 6, l = tid & 63;
  const int lq = l & 15, lg = l >> 4;
  const int wm = wid >> 2, wn = wid & 3;
  // XCD-chunked rasterization: xcd owns 4 m-tiles, sweeps n (A-band ~4.7MB in L2)
  const int bid = blockIdx.x;
  const int xcd = bid & 7, local = bid >> 3;
  const int ng = local >> 2, mi = local & 3;
  const int m0 = (xcd * 4 + mi) * 256, n0 = ng * 256;
  const int srow = tid >> 3;
  const int schunk = ((tid & 7) ^ (srow & 7)) * 8;   // pre-swizzled global chunk
  const int dslot = (tid & 7) * 8;                    // linear LDS dest
  const int laneA0 = lq * 128 + ((lg * 16) ^ ((lq & 7) << 4));
  const int laneA1 = lq * 128 + ((64 + lg * 16) ^ ((lq & 7) << 4));

  f32x4 acc[8][4] = {};
  bf16x8 a[4][2], bq[2][2][2];

  stage_tile(A, B, As[0], Bs[0], m0, n0, 0, srow, schunk, dslot);
  asm volatile("s_waitcnt vmcnt(0)" ::: "memory");
  __builtin_amdgcn_s_barrier();

  const char* a0p = (const char*)&As[0][0];
  const char* b0p = (const char*)&Bs[0][0];
  const char* a1p = (const char*)&As[1][0];
  const char* b1p = (const char*)&Bs[1][0];

  for (int t = 0; t < 36; t += 2) {
    // compute tile t from buf0; stage t+1 into buf1 (issued up-front, gated at tile end)
    stage_tile(A, B, As[1], Bs[1], m0, n0, (t + 1) * 64, srow, schunk, dslot);
    phase8<0, 0, true,  true >(a0p, b0p, wm, wn, laneA0, laneA1, a, bq, acc);
    phase8<0, 1, false, true >(a0p, b0p, wm, wn, laneA0, laneA1, a, bq, acc);
    phase8<1, 1, true,  false>(a0p, b0p, wm, wn, laneA0, laneA1, a, bq, acc);
    phase8<1, 0, false, false>(a0p, b0p, wm, wn, laneA0, laneA1, a, bq, acc);
    asm volatile("s_waitcnt vmcnt(0)" ::: "memory");
    __builtin_amdgcn_s_barrier();
    // compute tile t+1 from buf1; stage t+2 into buf0
    if (t + 2 < 36)
      stage_tile(A, B, As[0], Bs[0], m0, n0, (t + 2) * 64, srow, schunk, dslot);
    phase8<0, 0, true,  true >(a1p, b1p, wm, wn, laneA0, laneA1, a, bq, acc);
    phase8<0, 1, false, true >(a1p, b1p, wm, wn, laneA0, laneA1, a, bq, acc);
    phase8<1, 1, true,  false>(a1p, b1p, wm, wn, laneA0, laneA1, a, bq, acc);
    phase8<1, 0, false, false>(a1p, b1p, wm, wn, laneA0, laneA1, a, bq, acc);
    asm volatile("s_waitcnt vmcnt(0)" ::: "memory");
    __builtin_amdgcn_s_barrier();
  }

  if (EPI == 0) {
    const int mat = n0 / DIM;
    const int nb = n0 - mat * DIM;
    const float* bias = (mat == 0) ? b0 : (mat == 1) ? b1 : b2;
    __bf16* outp = (mat == 0) ? o0 : (mat == 1) ? o1 : o2;
#pragma unroll
    for (int mr = 0; mr < 8; ++mr) {
      const int gq = (m0 + wm * 128 + mr * 16) >> 4;
#pragma unroll
      for (int nr = 0; nr < 4; ++nr) {
        const int n = nb + wn * 64 + nr * 16 + lq;
        const int h = n / HD, d = n - (n / HD) * HD;
        const float bia = bias[n];
#pragma unroll
        for (int r = 0; r < 4; ++r) {
          const int bp = lg * 4 + r;
          outp[((size_t)(bp * NH + h) * SPS + gq) * HD + d] = (__bf16)(acc[mr][nr][r] + bia);
        }
      }
    }
  } else {
#pragma unroll
    for (int mr = 0; mr < 8; ++mr) {
      const int rbase = m0 + wm * 128 + mr * 16;
#pragma unroll
      for (int nr = 0; nr < 4; ++nr) {
        const int n = n0 + wn * 64 + nr * 16 + lq;
        const float bia = b0[n];
#pragma unroll
        for (int r = 0; r < 4; ++r)
          fout[(size_t)(rbase + lg * 4 + r) * DIM + n] = acc[mr][nr][r] + bia;
      }
    }
  }
}

// ---- 3D RoPE on q,k in attention layout; LDS cos/sin tables ----
__global__ __launch_bounds__(256) void rope_kernel(__bf16* __restrict__ q, __bf16* __restrict__ k)
{
  __shared__ float tc[640], ts_[640];
  const int tid = threadIdx.x;
  for (int i = tid; i < 640; i += 256) {
    int pos, jj = i & 15;
    if (i < 128)      pos = i >> 4;          // t axis: 8 pos
    else if (i < 384) pos = (i - 128) >> 4;  // h axis: 16 pos
    else              pos = (i - 384) >> 4;  // w axis: 16 pos
    const float invf = exp2f(-(float)jj * 0.83048202372184059f); // 10000^(-jj/16)
    float s, c;
    sincosf((float)pos * invf, &s, &c);
    tc[i] = c; ts_[i] = s;
  }
  __syncthreads();
  const int id = blockIdx.x * 256 + tid;       // [0, 2*16*24*512*3)
  const int cix = id % 3;
  int rest = id / 3;
  const int g = rest & 511; rest >>= 9;
  const int h = rest % 24;  rest /= 24;
  const int bp = rest & 15;
  const int tensor = rest >> 4;
  __bf16* base = (tensor ? k : q) + (((size_t)(bp * NH + h) * SPS + g) * HD + cix * 32);
  const int si = g * 4 + (bp >> 2);            // original sequence position
  const int pos = (cix == 0) ? (si >> 8) : (cix == 1) ? ((si >> 4) & 15) : (si & 15);
  const int toff = ((cix == 0) ? 0 : (cix == 1) ? 128 : 384) + pos * 16;
  bf16x8 e0 = *(const bf16x8*)(base);
  bf16x8 e1 = *(const bf16x8*)(base + 8);
  bf16x8 e2 = *(const bf16x8*)(base + 16);
  bf16x8 e3 = *(const bf16x8*)(base + 24);
  bf16x8 o0, o1, o2, o3;
#pragma unroll
  for (int j = 0; j < 8; ++j) {
    float c = tc[toff + j], s = ts_[toff + j];
    float x1 = (float)e0[j], x2 = (float)e2[j];
    o0[j] = (__bf16)(x1 * c - x2 * s);
    o2[j] = (__bf16)(x2 * c + x1 * s);
    c = tc[toff + 8 + j]; s = ts_[toff + 8 + j];
    x1 = (float)e1[j]; x2 = (float)e3[j];
    o1[j] = (__bf16)(x1 * c - x2 * s);
    o3[j] = (__bf16)(x2 * c + x1 * s);
  }
  *(bf16x8*)(base)      = o0;
  *(bf16x8*)(base + 8)  = o1;
  *(bf16x8*)(base + 16) = o2;
  *(bf16x8*)(base + 24) = o3;
}

// ---- flash attention: block = (qtile 64, h, b'); 4 waves x 16 q-rows ----
__global__ __launch_bounds__(256) void attn_kernel(
    const __bf16* __restrict__ q, const __bf16* __restrict__ k,
    const __bf16* __restrict__ v, __bf16* __restrict__ ao)
{
  __shared__ __bf16 Vt[96 * 72];        // V^T tile [d][key], padded rows
  __shared__ __bf16 Pl[4][16 * 72];     // per-wave P [q][key], padded rows
  const int tid = threadIdx.x;
  const int w = tid >> 6, l = tid & 63;
  const int lq = l & 15, lg = l >> 4;
  const int qt = blockIdx.x, h = blockIdx.y, bp = blockIdx.z;
  const size_t bh = ((size_t)bp * NH + h) * SPS;
  const __bf16* qb = q + bh * HD;
  const __bf16* kb = k + bh * HD;
  const __bf16* vb = v + bh * HD;
  bf16x8 qf[3];
  {
    const __bf16* qr = qb + (size_t)(qt * 64 + w * 16 + lq) * HD + lg * 8;
    qf[0] = *(const bf16x8*)(qr);
    qf[1] = *(const bf16x8*)(qr + 32);
    qf[2] = *(const bf16x8*)(qr + 64);
  }
  const float sc = 0.10206207261596575f * 1.4426950408889634f; // 96^-0.5 * log2(e)
  float m_run = -1e30f, l_run = 0.f;
  f32x4 o[6] = {};
  for (int kb0 = 0; kb0 < SPS; kb0 += 64) {
    __syncthreads();                     // previous PV reads of Vt done
#pragma unroll
    for (int p = 0; p < 3; ++p) {        // cooperative V^T staging
      const int lin = p * 256 + tid;
      const int row = lin / 12, c8 = (lin % 12) * 8;
      bf16x8 vv = *(const bf16x8*)(vb + (size_t)(kb0 + row) * HD + c8);
#pragma unroll
      for (int j = 0; j < 8; ++j) Vt[(c8 + j) * 72 + row] = vv[j];
    }
    __syncthreads();
    // S^T = K * Q^T  (rows=key, cols=q)  -> lane owns col q = lq
    f32x4 st[4];
#pragma unroll
    for (int t2 = 0; t2 < 4; ++t2) {
      const __bf16* kr = kb + (size_t)(kb0 + t2 * 16 + lq) * HD + lg * 8;
      bf16x8 k0f = *(const bf16x8*)(kr);
      bf16x8 k1f = *(const bf16x8*)(kr + 32);
      bf16x8 k2f = *(const bf16x8*)(kr + 64);
      f32x4 s = {};
      s = __builtin_amdgcn_mfma_f32_16x16x32_bf16(k0f, qf[0], s, 0, 0, 0);
      s = __builtin_amdgcn_mfma_f32_16x16x32_bf16(k1f, qf[1], s, 0, 0, 0);
      s = __builtin_amdgcn_mfma_f32_16x16x32_bf16(k2f, qf[2], s, 0, 0, 0);
      st[t2] = s;
    }
    // online softmax over this 64-key tile (per q = lq; keys split over lane groups)
    float tmax = -1e30f;
#pragma unroll
    for (int t2 = 0; t2 < 4; ++t2)
#pragma unroll
      for (int r = 0; r < 4; ++r) tmax = fmaxf(tmax, st[t2][r]);
    tmax = fmaxf(tmax, __shfl_xor(tmax, 16));
    tmax = fmaxf(tmax, __shfl_xor(tmax, 32));
    tmax *= sc;
    const float m_new = fmaxf(m_run, tmax);
    const float alpha = exp2f(m_run - m_new);
    float tsum = 0.f;
#pragma unroll
    for (int t2 = 0; t2 < 4; ++t2) {
      bf16x4 pb;
#pragma unroll
      for (int r = 0; r < 4; ++r) {
        const float p = exp2f(st[t2][r] * sc - m_new);
        tsum += p;
        pb[r] = (__bf16)p;
      }
      *(bf16x4*)&Pl[w][lq * 72 + t2 * 16 + lg * 4] = pb;  // P[q][key]
    }
    tsum += __shfl_xor(tsum, 16);
    tsum += __shfl_xor(tsum, 32);
    l_run = l_run * alpha + tsum;
    m_run = m_new;
    float al[4];
#pragma unroll
    for (int r = 0; r < 4; ++r) al[r] = __shfl(alpha, lg * 4 + r); // alpha for O-row q
#pragma unroll
    for (int ni = 0; ni < 6; ++ni)
#pragma unroll
      for (int r = 0; r < 4; ++r) o[ni][r] *= al[r];
    // O += P * V
#pragma unroll
    for (int ks = 0; ks < 2; ++ks) {
      bf16x8 pa = *(const bf16x8*)&Pl[w][lq * 72 + ks * 32 + lg * 8];
#pragma unroll
      for (int ni = 0; ni < 6; ++ni) {
        bf16x8 vf = *(const bf16x8*)&Vt[(ni * 16 + lq) * 72 + ks * 32 + lg * 8];
        o[ni] = __builtin_amdgcn_mfma_f32_16x16x32_bf16(pa, vf, o[ni], 0, 0, 0);
      }
    }
  }
  float linv[4];
#pragma unroll
  for (int r = 0; r < 4; ++r) linv[r] = 1.f / __shfl(l_run, lg * 4 + r);
#pragma unroll
  for (int ni = 0; ni < 6; ++ni)
#pragma unroll
    for (int r = 0; r < 4; ++r) {
      const int gq = qt * 64 + w * 16 + lg * 4 + r;
      const int d = ni * 16 + lq;
      ao[(size_t)(gq * 16 + bp) * DIM + h * HD + d] = (__bf16)(o[ni][r] * linv[r]);
    }
}

extern "C" void kernel_launch(void* const* d_in, const int* in_sizes, int n_in,
                              void* d_out, int out_size, void* d_ws, size_t ws_size,
                              hipStream_t stream) {
  const float* hs = (const float*)d_in[0];
  const float* wq = (const float*)d_in[1];
  const float* bq = (const float*)d_in[2];
  const float* wk = (const float*)d_in[3];
  const float* bk = (const float*)d_in[4];
  const float* wv = (const float*)d_in[5];
  const float* bv = (const float*)d_in[6];
  const float* wo = (const float*)d_in[7];
  const float* bo = (const float*)d_in[8];
  float* out = (float*)d_out;

  char* ws = (char*)d_ws;
  // workspace layout (bytes); total 193,462,272
  __bf16* wqkvT = (__bf16*)(ws);                               // 6912*2304*2 = 31,850,496
  __bf16* woT   = (__bf16*)(ws + 31850496);                    // 2304*2304*2 = 10,616,832
  __bf16* hsb   = (__bf16*)(ws + 42467328);                    // 8192*2304*2 = 37,748,736
  __bf16* qb    = (__bf16*)(ws + 80216064);                    // 37,748,736
  __bf16* kbuf  = (__bf16*)(ws + 117964800);                   // 37,748,736
  __bf16* vbuf  = (__bf16*)(ws + 155713536);                   // 37,748,736
  __bf16* ao    = hsb;  // reuse: hs_bf16 dead after gemm_qkv

  pack_w_kernel<<<dim3(36, 36, 4), 256, 0, stream>>>(wq, wk, wv, wo, wqkvT, woT);
  pack_hs_kernel<<<18432, 256, 0, stream>>>((const float4*)hs, (bf16x4*)hsb);
  gemm8p_kernel<0><<<864, 512, 0, stream>>>(hsb, wqkvT, bq, bk, bv, qb, kbuf, vbuf, nullptr);
  rope_kernel<<<4608, 256, 0, stream>>>(qb, kbuf);
  attn_kernel<<<dim3(8, NH, 16), 256, 0, stream>>>(qb, kbuf, vbuf, ao);
  gemm8p_kernel<1><<<288, 512, 0, stream>>>(ao, woT, bo, nullptr, nullptr, nullptr, nullptr, nullptr, out);
}

// Round 3
// 599.045 us; speedup vs baseline: 1.3170x; 1.1536x over previous
//
#include <hip/hip_runtime.h>
#include <hip/hip_bf16.h>

typedef __attribute__((ext_vector_type(8))) __bf16 bf16x8;
typedef __attribute__((ext_vector_type(4))) __bf16 bf16x4;
typedef __attribute__((ext_vector_type(4))) float  f32x4;

#define DIM   2304
#define NH    24
#define HD    96
#define SPS   512

// ---- async global->LDS, 16B per lane (dest = wave-uniform base + lane*16) ----
__device__ __forceinline__ void gload16(const void* gp, void* lp) {
  __builtin_amdgcn_global_load_lds(
      (__attribute__((address_space(1))) void*)(unsigned long long)gp,
      (__attribute__((address_space(3))) void*)lp, 16, 0, 0);
}

// ---- weight transpose + bf16 cast: dst[n][k] = (bf16) src[k][n] ----
__global__ __launch_bounds__(256) void pack_w_kernel(
    const float* __restrict__ wq, const float* __restrict__ wk,
    const float* __restrict__ wv, const float* __restrict__ wo,
    __bf16* __restrict__ dqkv, __bf16* __restrict__ dwo)
{
  __shared__ float t[64][65];
  const int z = blockIdx.z;
  const float* src = (z == 0) ? wq : (z == 1) ? wk : (z == 2) ? wv : wo;
  __bf16* dst = (z < 3) ? (dqkv + (size_t)z * DIM * DIM) : dwo;
  const int n0 = blockIdx.x * 64, k0 = blockIdx.y * 64;
  const int tx = threadIdx.x & 63, ty = threadIdx.x >> 6;
#pragma unroll
  for (int j = 0; j < 64; j += 4)
    t[ty + j][tx] = src[(size_t)(k0 + ty + j) * DIM + n0 + tx];
  __syncthreads();
#pragma unroll
  for (int j = 0; j < 64; j += 4)
    dst[(size_t)(n0 + ty + j) * DIM + k0 + tx] = (__bf16)t[tx][ty + j];
}

// ---- hidden_states fp32 -> bf16 ----
__global__ __launch_bounds__(256) void pack_hs_kernel(
    const float4* __restrict__ src, bf16x4* __restrict__ dst)
{
  const int i = blockIdx.x * 256 + threadIdx.x;
  const float4 f = src[i];
  bf16x4 o = { (__bf16)f.x, (__bf16)f.y, (__bf16)f.z, (__bf16)f.w };
  dst[i] = o;
}

// ================= 256x256 8-phase GEMM, counted-vmcnt pipeline =================
// A [M][K], B [N][K] row-major bf16. 512 thr = 8 waves (2M x 4N), per-wave 128x64,
// BK=64, LDS 128KB dbuf, st_16-style XOR swizzle both-sides. Stage(t+2) is issued
// into the buffer being read at tile t (B-half after ph2, A-half after ph3 -- those
// regions are globally consumed by then); tile-end gate is vmcnt(8): waits only for
// stage(t+1) (issued one full tile earlier), never draining the queue.

__device__ __forceinline__ void stage_half(
    const __bf16* __restrict__ X, __bf16* lX, int r0, int k0,
    int srow, int schunk, int dslot)
{
#pragma unroll
  for (int j = 0; j < 4; ++j)
    gload16(X + (size_t)(r0 + j * 64 + srow) * DIM + k0 + schunk,
            lX + (j * 64 + srow) * 64 + dslot);
}

template<int H, int Q, bool LA, bool LB>
__device__ __forceinline__ void phase8(
    const char* ab, const char* bb, int wm, int wn, int laneA0, int laneA1,
    bf16x8 (&a)[4][2], bf16x8 (&bq)[2][2][2], f32x4 (&acc)[8][4])
{
  if (LA) {
#pragma unroll
    for (int fm = 0; fm < 4; ++fm) {
      a[fm][0] = *(const bf16x8*)(ab + (wm * 128 + H * 64 + fm * 16) * 128 + laneA0);
      a[fm][1] = *(const bf16x8*)(ab + (wm * 128 + H * 64 + fm * 16) * 128 + laneA1);
    }
  }
  if (LB) {
#pragma unroll
    for (int fn = 0; fn < 2; ++fn) {
      bq[Q][fn][0] = *(const bf16x8*)(bb + (wn * 64 + Q * 32 + fn * 16) * 128 + laneA0);
      bq[Q][fn][1] = *(const bf16x8*)(bb + (wn * 64 + Q * 32 + fn * 16) * 128 + laneA1);
    }
  }
  __builtin_amdgcn_s_barrier();
  asm volatile("s_waitcnt lgkmcnt(0)" ::: "memory");
  __builtin_amdgcn_s_setprio(1);
#pragma unroll
  for (int fm = 0; fm < 4; ++fm)
#pragma unroll
    for (int fn = 0; fn < 2; ++fn)
#pragma unroll
      for (int kk = 0; kk < 2; ++kk)
        acc[H * 4 + fm][Q * 2 + fn] = __builtin_amdgcn_mfma_f32_16x16x32_bf16(
            a[fm][kk], bq[Q][fn][kk], acc[H * 4 + fm][Q * 2 + fn], 0, 0, 0);
  __builtin_amdgcn_s_setprio(0);
  __builtin_amdgcn_s_barrier();
}

// EPI 0: fused-QKV scatter + bias + 3D-RoPE epilogue (bf16 attn layout). EPI 1: fp32 C.
template<int EPI>
__global__ __launch_bounds__(512, 2) void gemm8p_kernel(
    const __bf16* __restrict__ A, const __bf16* __restrict__ B,
    const float* __restrict__ b0, const float* __restrict__ b1, const float* __restrict__ b2,
    __bf16* __restrict__ o0, __bf16* __restrict__ o1, __bf16* __restrict__ o2,
    float* __restrict__ fout)
{
  __shared__ __align__(16) __bf16 As[2][256 * 64];
  __shared__ __align__(16) __bf16 Bs[2][256 * 64];
  __shared__ float tcos[640], tsin[640];
  const int tid = threadIdx.x;
  if (EPI == 0) {
    for (int i = tid; i < 640; i += 512) {
      int pos, jj = i & 15;
      if (i < 128)      pos = i >> 4;
      else if (i < 384) pos = (i - 128) >> 4;
      else              pos = (i - 384) >> 4;
      const float invf = exp2f(-(float)jj * 0.83048202372184059f); // 10000^(-jj/16)
      float s, c;
      sincosf((float)pos * invf, &s, &c);
      tcos[i] = c; tsin[i] = s;
    }
  }
  const int wid = tid >> 6, l = tid & 63;
  const int lq = l & 15, lg = l >> 4;
  const int wm = wid >> 2, wn = wid & 3;
  const int bid = blockIdx.x;
  const int xcd = bid & 7, local = bid >> 3;
  const int ng = local >> 2, mi = local & 3;
  const int m0 = (xcd * 4 + mi) * 256, n0 = ng * 256;
  const int srow = tid >> 3;
  const int schunk = ((tid & 7) ^ (srow & 7)) * 8;
  const int dslot = (tid & 7) * 8;
  const int laneA0 = lq * 128 + ((lg * 16) ^ ((lq & 7) << 4));
  const int laneA1 = lq * 128 + ((64 + lg * 16) ^ ((lq & 7) << 4));

  f32x4 acc[8][4] = {};
  bf16x8 a[4][2], bq[2][2][2];

  // prologue: stage tiles 0,1
  stage_half(A, As[0], m0, 0, srow, schunk, dslot);
  stage_half(B, Bs[0], n0, 0, srow, schunk, dslot);
  stage_half(A, As[1], m0, 64, srow, schunk, dslot);
  stage_half(B, Bs[1], n0, 64, srow, schunk, dslot);
  asm volatile("s_waitcnt vmcnt(8)" ::: "memory");   // wait tile 0 only
  __builtin_amdgcn_s_barrier();

  const char* a0p = (const char*)&As[0][0];
  const char* b0p = (const char*)&Bs[0][0];
  const char* a1p = (const char*)&As[1][0];
  const char* b1p = (const char*)&Bs[1][0];

#define TILE_STAGED(AP, BP, SA, SB, KN)                                        \
  phase8<0, 0, true,  true >(AP, BP, wm, wn, laneA0, laneA1, a, bq, acc);      \
  phase8<0, 1, false, true >(AP, BP, wm, wn, laneA0, laneA1, a, bq, acc);      \
  stage_half(B, SB, n0, KN, srow, schunk, dslot);                              \
  phase8<1, 1, true,  false>(AP, BP, wm, wn, laneA0, laneA1, a, bq, acc);      \
  stage_half(A, SA, m0, KN, srow, schunk, dslot);                              \
  phase8<1, 0, false, false>(AP, BP, wm, wn, laneA0, laneA1, a, bq, acc);      \
  asm volatile("s_waitcnt vmcnt(8)" ::: "memory");                             \
  __builtin_amdgcn_s_barrier();

#define TILE_PLAIN(AP, BP)                                                     \
  phase8<0, 0, true,  true >(AP, BP, wm, wn, laneA0, laneA1, a, bq, acc);      \
  phase8<0, 1, false, true >(AP, BP, wm, wn, laneA0, laneA1, a, bq, acc);      \
  phase8<1, 1, true,  false>(AP, BP, wm, wn, laneA0, laneA1, a, bq, acc);      \
  phase8<1, 0, false, false>(AP, BP, wm, wn, laneA0, laneA1, a, bq, acc);

  for (int tt = 0; tt < 34; tt += 2) {
    // tile tt (buf0): stage tt+2 -> buf0 (B after ph2, A after ph3); gate waits stage(tt+1)
    TILE_STAGED(a0p, b0p, As[0], Bs[0], (tt + 2) * 64)
    // tile tt+1 (buf1): stage tt+3 -> buf1; gate waits stage(tt+2)
    TILE_STAGED(a1p, b1p, As[1], Bs[1], (tt + 3) * 64)
  }
  // tile 34 (buf0): nothing left to stage; drain stage(35) fully
  TILE_PLAIN(a0p, b0p)
  asm volatile("s_waitcnt vmcnt(0)" ::: "memory");
  __builtin_amdgcn_s_barrier();
  // tile 35 (buf1): last compute, no gate
  TILE_PLAIN(a1p, b1p)
#undef TILE_STAGED
#undef TILE_PLAIN

  if (EPI == 0) {
    const int mat = n0 / DIM;
    const int nb = n0 - mat * DIM;
    const float* bias = (mat == 0) ? b0 : (mat == 1) ? b1 : b2;
    __bf16* outp = (mat == 0) ? o0 : (mat == 1) ? o1 : o2;
#pragma unroll
    for (int mr = 0; mr < 8; ++mr) {
      const int gq = (m0 + wm * 128 + mr * 16) >> 4;
      const int si = gq * 4 + lg;                     // original seq position (r-independent)
      const int pos3[3] = { si >> 8, (si >> 4) & 15, si & 15 };
#pragma unroll
      for (int p = 0; p < 2; ++p) {                   // fragment pairs (2p, 2p+1) = rope (lo,hi)
        const int nlo = nb + wn * 64 + (2 * p) * 16 + lq;
        const int nhi = nlo + 16;
        const int hlo = nlo / HD, dlo = nlo - hlo * HD;
        const int hhi = nhi / HD, dhi = nhi - hhi * HD;
        const float blo = bias[nlo], bhi = bias[nhi];
        float c = 1.f, s = 0.f;
        if (mat < 2) {
          const int cix = dlo >> 5;                   // axis of this 32-block
          const int toff = ((cix == 0) ? 0 : (cix == 1) ? 128 : 384) + pos3[cix] * 16 + lq;
          c = tcos[toff]; s = tsin[toff];
        }
#pragma unroll
        for (int r = 0; r < 4; ++r) {
          const int bp = lg * 4 + r;
          const float x1 = acc[mr][2 * p][r] + blo;
          const float x2 = acc[mr][2 * p + 1][r] + bhi;
          float y1 = x1, y2 = x2;
          if (mat < 2) { y1 = x1 * c - x2 * s; y2 = x2 * c + x1 * s; }
          outp[((size_t)(bp * NH + hlo) * SPS + gq) * HD + dlo] = (__bf16)y1;
          outp[((size_t)(bp * NH + hhi) * SPS + gq) * HD + dhi] = (__bf16)y2;
        }
      }
    }
  } else {
#pragma unroll
    for (int mr = 0; mr < 8; ++mr) {
      const int rbase = m0 + wm * 128 + mr * 16;
#pragma unroll
      for (int nr = 0; nr < 4; ++nr) {
        const int n = n0 + wn * 64 + nr * 16 + lq;
        const float bia = b0[n];
#pragma unroll
        for (int r = 0; r < 4; ++r)
          fout[(size_t)(rbase + lg * 4 + r) * DIM + n] = acc[mr][nr][r] + bia;
      }
    }
  }
}

// ---- flash attention: block = (qtile 64, h, b'); 4 waves x 16 q-rows ----
__global__ __launch_bounds__(256) void attn_kernel(
    const __bf16* __restrict__ q, const __bf16* __restrict__ k,
    const __bf16* __restrict__ v, __bf16* __restrict__ ao)
{
  __shared__ __bf16 Vt[96 * 72];        // V^T tile [d][key], padded rows
  __shared__ __bf16 Pl[4][16 * 72];     // per-wave P [q][key], padded rows
  const int tid = threadIdx.x;
  const int w = tid >> 6, l = tid & 63;
  const int lq = l & 15, lg = l >> 4;
  const int qt = blockIdx.x, h = blockIdx.y, bp = blockIdx.z;
  const size_t bh = ((size_t)bp * NH + h) * SPS;
  const __bf16* qb = q + bh * HD;
  const __bf16* kb = k + bh * HD;
  const __bf16* vb = v + bh * HD;
  bf16x8 qf[3];
  {
    const __bf16* qr = qb + (size_t)(qt * 64 + w * 16 + lq) * HD + lg * 8;
    qf[0] = *(const bf16x8*)(qr);
    qf[1] = *(const bf16x8*)(qr + 32);
    qf[2] = *(const bf16x8*)(qr + 64);
  }
  const float sc = 0.10206207261596575f * 1.4426950408889634f; // 96^-0.5 * log2(e)
  float m_run = -1e30f, l_run = 0.f;
  f32x4 o[6] = {};
  for (int kb0 = 0; kb0 < SPS; kb0 += 64) {
    __syncthreads();
#pragma unroll
    for (int p = 0; p < 3; ++p) {        // cooperative V^T staging
      const int lin = p * 256 + tid;
      const int row = lin / 12, c8 = (lin % 12) * 8;
      bf16x8 vv = *(const bf16x8*)(vb + (size_t)(kb0 + row) * HD + c8);
#pragma unroll
      for (int j = 0; j < 8; ++j) Vt[(c8 + j) * 72 + row] = vv[j];
    }
    __syncthreads();
    f32x4 st[4];
#pragma unroll
    for (int t2 = 0; t2 < 4; ++t2) {
      const __bf16* kr = kb + (size_t)(kb0 + t2 * 16 + lq) * HD + lg * 8;
      bf16x8 k0f = *(const bf16x8*)(kr);
      bf16x8 k1f = *(const bf16x8*)(kr + 32);
      bf16x8 k2f = *(const bf16x8*)(kr + 64);
      f32x4 s = {};
      s = __builtin_amdgcn_mfma_f32_16x16x32_bf16(k0f, qf[0], s, 0, 0, 0);
      s = __builtin_amdgcn_mfma_f32_16x16x32_bf16(k1f, qf[1], s, 0, 0, 0);
      s = __builtin_amdgcn_mfma_f32_16x16x32_bf16(k2f, qf[2], s, 0, 0, 0);
      st[t2] = s;
    }
    float tmax = -1e30f;
#pragma unroll
    for (int t2 = 0; t2 < 4; ++t2)
#pragma unroll
      for (int r = 0; r < 4; ++r) tmax = fmaxf(tmax, st[t2][r]);
    tmax = fmaxf(tmax, __shfl_xor(tmax, 16));
    tmax = fmaxf(tmax, __shfl_xor(tmax, 32));
    tmax *= sc;
    const float m_new = fmaxf(m_run, tmax);
    const float alpha = exp2f(m_run - m_new);
    float tsum = 0.f;
#pragma unroll
    for (int t2 = 0; t2 < 4; ++t2) {
      bf16x4 pb;
#pragma unroll
      for (int r = 0; r < 4; ++r) {
        const float p = exp2f(st[t2][r] * sc - m_new);
        tsum += p;
        pb[r] = (__bf16)p;
      }
      *(bf16x4*)&Pl[w][lq * 72 + t2 * 16 + lg * 4] = pb;
    }
    tsum += __shfl_xor(tsum, 16);
    tsum += __shfl_xor(tsum, 32);
    l_run = l_run * alpha + tsum;
    m_run = m_new;
    float al[4];
#pragma unroll
    for (int r = 0; r < 4; ++r) al[r] = __shfl(alpha, lg * 4 + r);
#pragma unroll
    for (int ni = 0; ni < 6; ++ni)
#pragma unroll
      for (int r = 0; r < 4; ++r) o[ni][r] *= al[r];
#pragma unroll
    for (int ks = 0; ks < 2; ++ks) {
      bf16x8 pa = *(const bf16x8*)&Pl[w][lq * 72 + ks * 32 + lg * 8];
#pragma unroll
      for (int ni = 0; ni < 6; ++ni) {
        bf16x8 vf = *(const bf16x8*)&Vt[(ni * 16 + lq) * 72 + ks * 32 + lg * 8];
        o[ni] = __builtin_amdgcn_mfma_f32_16x16x32_bf16(pa, vf, o[ni], 0, 0, 0);
      }
    }
  }
  float linv[4];
#pragma unroll
  for (int r = 0; r < 4; ++r) linv[r] = 1.f / __shfl(l_run, lg * 4 + r);
#pragma unroll
  for (int ni = 0; ni < 6; ++ni)
#pragma unroll
    for (int r = 0; r < 4; ++r) {
      const int gq = qt * 64 + w * 16 + lg * 4 + r;
      const int d = ni * 16 + lq;
      ao[(size_t)(gq * 16 + bp) * DIM + h * HD + d] = (__bf16)(o[ni][r] * linv[r]);
    }
}

extern "C" void kernel_launch(void* const* d_in, const int* in_sizes, int n_in,
                              void* d_out, int out_size, void* d_ws, size_t ws_size,
                              hipStream_t stream) {
  const float* hs = (const float*)d_in[0];
  const float* wq = (const float*)d_in[1];
  const float* bq = (const float*)d_in[2];
  const float* wk = (const float*)d_in[3];
  const float* bk = (const float*)d_in[4];
  const float* wv = (const float*)d_in[5];
  const float* bv = (const float*)d_in[6];
  const float* wo = (const float*)d_in[7];
  const float* bo = (const float*)d_in[8];
  float* out = (float*)d_out;

  char* ws = (char*)d_ws;
  __bf16* wqkvT = (__bf16*)(ws);                               // 31,850,496
  __bf16* woT   = (__bf16*)(ws + 31850496);                    // 10,616,832
  __bf16* hsb   = (__bf16*)(ws + 42467328);                    // 37,748,736
  __bf16* qb    = (__bf16*)(ws + 80216064);                    // 37,748,736
  __bf16* kbuf  = (__bf16*)(ws + 117964800);                   // 37,748,736
  __bf16* vbuf  = (__bf16*)(ws + 155713536);                   // 37,748,736
  __bf16* ao    = hsb;  // reuse: hs_bf16 dead after gemm_qkv

  pack_w_kernel<<<dim3(36, 36, 4), 256, 0, stream>>>(wq, wk, wv, wo, wqkvT, woT);
  pack_hs_kernel<<<18432, 256, 0, stream>>>((const float4*)hs, (bf16x4*)hsb);
  gemm8p_kernel<0><<<864, 512, 0, stream>>>(hsb, wqkvT, bq, bk, bv, qb, kbuf, vbuf, nullptr);
  attn_kernel<<<dim3(8, NH, 16), 256, 0, stream>>>(qb, kbuf, vbuf, ao);
  gemm8p_kernel<1><<<288, 512, 0, stream>>>(ao, woT, bo, nullptr, nullptr, nullptr, nullptr, nullptr, out);
}

// Round 4
// 570.580 us; speedup vs baseline: 1.3827x; 1.0499x over previous
//
#include <hip/hip_runtime.h>
#include <hip/hip_bf16.h>

typedef __attribute__((ext_vector_type(8))) __bf16 bf16x8;
typedef __attribute__((ext_vector_type(4))) __bf16 bf16x4;
typedef __attribute__((ext_vector_type(4))) float  f32x4;

#define DIM   2304
#define NH    24
#define HD    96
#define SPS   512

// ---- async global->LDS, 16B per lane (dest = wave-uniform base + lane*16) ----
__device__ __forceinline__ void gload16(const void* gp, void* lp) {
  __builtin_amdgcn_global_load_lds(
      (__attribute__((address_space(1))) void*)(unsigned long long)gp,
      (__attribute__((address_space(3))) void*)lp, 16, 0, 0);
}

// ---- weight transpose + bf16 cast: dst[n][k] = (bf16) src[k][n] ----
__global__ __launch_bounds__(256) void pack_w_kernel(
    const float* __restrict__ wq, const float* __restrict__ wk,
    const float* __restrict__ wv, const float* __restrict__ wo,
    __bf16* __restrict__ dqkv, __bf16* __restrict__ dwo)
{
  __shared__ float t[64][65];
  const int z = blockIdx.z;
  const float* src = (z == 0) ? wq : (z == 1) ? wk : (z == 2) ? wv : wo;
  __bf16* dst = (z < 3) ? (dqkv + (size_t)z * DIM * DIM) : dwo;
  const int n0 = blockIdx.x * 64, k0 = blockIdx.y * 64;
  const int tx = threadIdx.x & 63, ty = threadIdx.x >> 6;
#pragma unroll
  for (int j = 0; j < 64; j += 4)
    t[ty + j][tx] = src[(size_t)(k0 + ty + j) * DIM + n0 + tx];
  __syncthreads();
#pragma unroll
  for (int j = 0; j < 64; j += 4)
    dst[(size_t)(n0 + ty + j) * DIM + k0 + tx] = (__bf16)t[tx][ty + j];
}

// ---- hidden_states fp32 -> bf16 ----
__global__ __launch_bounds__(256) void pack_hs_kernel(
    const float4* __restrict__ src, bf16x4* __restrict__ dst)
{
  const int i = blockIdx.x * 256 + threadIdx.x;
  const float4 f = src[i];
  bf16x4 o = { (__bf16)f.x, (__bf16)f.y, (__bf16)f.z, (__bf16)f.w };
  dst[i] = o;
}

// ================= 8-phase GEMM, counted-vmcnt pipeline =================
// A [M][K], B [N][K] row-major bf16. 512 thr = 8 waves (2M x 4N), BK=64,
// XOR-swizzled LDS both-sides. EPI0: 256x256 tile (MF=4), QKV scatter+RoPE.
// EPI1: 128x256 tile (MF=2), fp32 C (smaller blocks to cut CU-round tail).

template<int NJ>
__device__ __forceinline__ void stage_half(
    const __bf16* __restrict__ X, __bf16* lX, int r0, int k0,
    int srow, int schunk, int dslot)
{
#pragma unroll
  for (int j = 0; j < NJ; ++j)
    gload16(X + (size_t)(r0 + j * 64 + srow) * DIM + k0 + schunk,
            lX + (j * 64 + srow) * 64 + dslot);
}

template<int MF, int H, int Q, bool LA, bool LB>
__device__ __forceinline__ void phase8(
    const char* ab, const char* bb, int wm, int wn, int laneA0, int laneA1,
    bf16x8 (&a)[MF][2], bf16x8 (&bq)[2][2][2], f32x4 (&acc)[2 * MF][4])
{
  if (LA) {
#pragma unroll
    for (int fm = 0; fm < MF; ++fm) {
      a[fm][0] = *(const bf16x8*)(ab + (wm * (MF * 32) + H * (MF * 16) + fm * 16) * 128 + laneA0);
      a[fm][1] = *(const bf16x8*)(ab + (wm * (MF * 32) + H * (MF * 16) + fm * 16) * 128 + laneA1);
    }
  }
  if (LB) {
#pragma unroll
    for (int fn = 0; fn < 2; ++fn) {
      bq[Q][fn][0] = *(const bf16x8*)(bb + (wn * 64 + Q * 32 + fn * 16) * 128 + laneA0);
      bq[Q][fn][1] = *(const bf16x8*)(bb + (wn * 64 + Q * 32 + fn * 16) * 128 + laneA1);
    }
  }
  __builtin_amdgcn_s_barrier();
  asm volatile("s_waitcnt lgkmcnt(0)" ::: "memory");
  __builtin_amdgcn_s_setprio(1);
#pragma unroll
  for (int fm = 0; fm < MF; ++fm)
#pragma unroll
    for (int fn = 0; fn < 2; ++fn)
#pragma unroll
      for (int kk = 0; kk < 2; ++kk)
        acc[H * MF + fm][Q * 2 + fn] = __builtin_amdgcn_mfma_f32_16x16x32_bf16(
            a[fm][kk], bq[Q][fn][kk], acc[H * MF + fm][Q * 2 + fn], 0, 0, 0);
  __builtin_amdgcn_s_setprio(0);
  __builtin_amdgcn_s_barrier();
}

template<int EPI>
__global__ __launch_bounds__(512, 2) void gemm8p_kernel(
    const __bf16* __restrict__ A, const __bf16* __restrict__ B,
    const float* __restrict__ b0, const float* __restrict__ b1, const float* __restrict__ b2,
    __bf16* __restrict__ o0, __bf16* __restrict__ o1, __bf16* __restrict__ o2,
    float* __restrict__ fout)
{
  constexpr int MF = (EPI == 0) ? 4 : 2;         // A fragments per phase-half
  constexpr int MROWS = MF * 64;                 // 256 or 128
  __shared__ __align__(16) __bf16 As[2][MROWS * 64];
  __shared__ __align__(16) __bf16 Bs[2][256 * 64];
  __shared__ float tcos[640], tsin[640];
  const int tid = threadIdx.x;
  if (EPI == 0) {
    for (int i = tid; i < 640; i += 512) {
      int pos, jj = i & 15;
      if (i < 128)      pos = i >> 4;
      else if (i < 384) pos = (i - 128) >> 4;
      else              pos = (i - 384) >> 4;
      const float invf = exp2f(-(float)jj * 0.83048202372184059f); // 10000^(-jj/16)
      float s, c;
      sincosf((float)pos * invf, &s, &c);
      tcos[i] = c; tsin[i] = s;
    }
  }
  const int wid = tid >> 6, l = tid & 63;
  const int lq = l & 15, lg = l >> 4;
  const int wm = wid >> 2, wn = wid & 3;
  const int bid = blockIdx.x;
  const int xcd = bid & 7, local = bid >> 3;
  int m0, n0;
  if (EPI == 0) {                                 // 864 blocks: 32 m x 27 n
    m0 = (xcd * 4 + (local & 3)) * 256;
    n0 = (local >> 2) * 256;
  } else {                                        // 576 blocks: 64 m x 9 n
    m0 = (xcd * 8 + (local & 7)) * 128;
    n0 = (local >> 3) * 256;
  }
  const int srow = tid >> 3;
  const int schunk = ((tid & 7) ^ (srow & 7)) * 8;
  const int dslot = (tid & 7) * 8;
  const int laneA0 = lq * 128 + ((lg * 16) ^ ((lq & 7) << 4));
  const int laneA1 = lq * 128 + ((64 + lg * 16) ^ ((lq & 7) << 4));

  f32x4 acc[2 * MF][4] = {};
  bf16x8 a[MF][2], bq[2][2][2];

  // prologue: stage tiles 0,1 (MF+4 loads each)
  stage_half<MF>(A, As[0], m0, 0, srow, schunk, dslot);
  stage_half<4>(B, Bs[0], n0, 0, srow, schunk, dslot);
  stage_half<MF>(A, As[1], m0, 64, srow, schunk, dslot);
  stage_half<4>(B, Bs[1], n0, 64, srow, schunk, dslot);
  if (EPI == 0) asm volatile("s_waitcnt vmcnt(8)" ::: "memory");
  else          asm volatile("s_waitcnt vmcnt(6)" ::: "memory");
  __builtin_amdgcn_s_barrier();

  const char* a0p = (const char*)&As[0][0];
  const char* b0p = (const char*)&Bs[0][0];
  const char* a1p = (const char*)&As[1][0];
  const char* b1p = (const char*)&Bs[1][0];

#define TILE_STAGED(AP, BP, SA, SB, KN)                                          \
  phase8<MF, 0, 0, true,  true >(AP, BP, wm, wn, laneA0, laneA1, a, bq, acc);    \
  phase8<MF, 0, 1, false, true >(AP, BP, wm, wn, laneA0, laneA1, a, bq, acc);    \
  stage_half<4>(B, SB, n0, KN, srow, schunk, dslot);                             \
  phase8<MF, 1, 1, true,  false>(AP, BP, wm, wn, laneA0, laneA1, a, bq, acc);    \
  stage_half<MF>(A, SA, m0, KN, srow, schunk, dslot);                            \
  phase8<MF, 1, 0, false, false>(AP, BP, wm, wn, laneA0, laneA1, a, bq, acc);    \
  if (EPI == 0) asm volatile("s_waitcnt vmcnt(8)" ::: "memory");                 \
  else          asm volatile("s_waitcnt vmcnt(6)" ::: "memory");                 \
  __builtin_amdgcn_s_barrier();

#define TILE_PLAIN(AP, BP)                                                       \
  phase8<MF, 0, 0, true,  true >(AP, BP, wm, wn, laneA0, laneA1, a, bq, acc);    \
  phase8<MF, 0, 1, false, true >(AP, BP, wm, wn, laneA0, laneA1, a, bq, acc);    \
  phase8<MF, 1, 1, true,  false>(AP, BP, wm, wn, laneA0, laneA1, a, bq, acc);    \
  phase8<MF, 1, 0, false, false>(AP, BP, wm, wn, laneA0, laneA1, a, bq, acc);

  for (int tt = 0; tt < 34; tt += 2) {
    TILE_STAGED(a0p, b0p, As[0], Bs[0], (tt + 2) * 64)
    TILE_STAGED(a1p, b1p, As[1], Bs[1], (tt + 3) * 64)
  }
  TILE_PLAIN(a0p, b0p)
  asm volatile("s_waitcnt vmcnt(0)" ::: "memory");
  __builtin_amdgcn_s_barrier();
  TILE_PLAIN(a1p, b1p)
#undef TILE_STAGED
#undef TILE_PLAIN

  if (EPI == 0) {
    const int mat = n0 / DIM;
    const int nb = n0 - mat * DIM;
    const float* bias = (mat == 0) ? b0 : (mat == 1) ? b1 : b2;
    __bf16* outp = (mat == 0) ? o0 : (mat == 1) ? o1 : o2;
#pragma unroll
    for (int mr = 0; mr < 8; ++mr) {
      const int gq = (m0 + wm * 128 + mr * 16) >> 4;
      const int si = gq * 4 + lg;
      const int pos3[3] = { si >> 8, (si >> 4) & 15, si & 15 };
#pragma unroll
      for (int p = 0; p < 2; ++p) {
        const int nlo = nb + wn * 64 + (2 * p) * 16 + lq;
        const int nhi = nlo + 16;
        const int hlo = nlo / HD, dlo = nlo - hlo * HD;
        const int hhi = nhi / HD, dhi = nhi - hhi * HD;
        const float blo = bias[nlo], bhi = bias[nhi];
        float c = 1.f, s = 0.f;
        if (mat < 2) {
          const int cix = dlo >> 5;
          const int toff = ((cix == 0) ? 0 : (cix == 1) ? 128 : 384) + pos3[cix] * 16 + lq;
          c = tcos[toff]; s = tsin[toff];
        }
#pragma unroll
        for (int r = 0; r < 4; ++r) {
          const int bp = lg * 4 + r;
          const float x1 = acc[mr][2 * p][r] + blo;
          const float x2 = acc[mr][2 * p + 1][r] + bhi;
          float y1 = x1, y2 = x2;
          if (mat < 2) { y1 = x1 * c - x2 * s; y2 = x2 * c + x1 * s; }
          outp[((size_t)(bp * NH + hlo) * SPS + gq) * HD + dlo] = (__bf16)y1;
          outp[((size_t)(bp * NH + hhi) * SPS + gq) * HD + dhi] = (__bf16)y2;
        }
      }
    }
  } else {
#pragma unroll
    for (int mr = 0; mr < 4; ++mr) {
      const int rbase = m0 + wm * 64 + mr * 16;
#pragma unroll
      for (int nr = 0; nr < 4; ++nr) {
        const int n = n0 + wn * 64 + nr * 16 + lq;
        const float bia = b0[n];
#pragma unroll
        for (int r = 0; r < 4; ++r)
          fout[(size_t)(rbase + lg * 4 + r) * DIM + n] = acc[mr][nr][r] + bia;
      }
    }
  }
}

// ---- flash attention: 4 waves x 16 q-rows; XCD-chunked grid so the 8 q-tile
//      blocks of one (bp,h) share an XCD's L2 (KV fetched once, not 8x) ----
__global__ __launch_bounds__(256) void attn_kernel(
    const __bf16* __restrict__ q, const __bf16* __restrict__ k,
    const __bf16* __restrict__ v, __bf16* __restrict__ ao)
{
  __shared__ __bf16 Vt[96 * 72];        // V^T tile [d][key], padded rows
  __shared__ __bf16 Pl[4][16 * 72];     // per-wave P [q][key], padded rows
  const int tid = threadIdx.x;
  const int w = tid >> 6, l = tid & 63;
  const int lq = l & 15, lg = l >> 4;
  // bijective chunked XCD swizzle over 3072 blocks (384 per XCD), qt innermost
  const int bid = blockIdx.x;
  const int swz = (bid & 7) * 384 + (bid >> 3);
  const int qt = swz & 7;
  const int h  = (swz >> 3) % NH;
  const int bp = swz / (NH * 8);
  const size_t bh = ((size_t)bp * NH + h) * SPS;
  const __bf16* qb = q + bh * HD;
  const __bf16* kb = k + bh * HD;
  const __bf16* vb = v + bh * HD;
  bf16x8 qf[3];
  {
    const __bf16* qr = qb + (size_t)(qt * 64 + w * 16 + lq) * HD + lg * 8;
    qf[0] = *(const bf16x8*)(qr);
    qf[1] = *(const bf16x8*)(qr + 32);
    qf[2] = *(const bf16x8*)(qr + 64);
  }
  const float sc = 0.10206207261596575f * 1.4426950408889634f; // 96^-0.5 * log2(e)
  float m_run = -1e30f, l_run = 0.f;
  f32x4 o[6] = {};
  for (int kb0 = 0; kb0 < SPS; kb0 += 64) {
    __syncthreads();
#pragma unroll
    for (int p = 0; p < 3; ++p) {        // cooperative V^T staging
      const int lin = p * 256 + tid;
      const int row = lin / 12, c8 = (lin % 12) * 8;
      bf16x8 vv = *(const bf16x8*)(vb + (size_t)(kb0 + row) * HD + c8);
#pragma unroll
      for (int j = 0; j < 8; ++j) Vt[(c8 + j) * 72 + row] = vv[j];
    }
    __syncthreads();
    f32x4 st[4];
#pragma unroll
    for (int t2 = 0; t2 < 4; ++t2) {
      const __bf16* kr = kb + (size_t)(kb0 + t2 * 16 + lq) * HD + lg * 8;
      bf16x8 k0f = *(const bf16x8*)(kr);
      bf16x8 k1f = *(const bf16x8*)(kr + 32);
      bf16x8 k2f = *(const bf16x8*)(kr + 64);
      f32x4 s = {};
      s = __builtin_amdgcn_mfma_f32_16x16x32_bf16(k0f, qf[0], s, 0, 0, 0);
      s = __builtin_amdgcn_mfma_f32_16x16x32_bf16(k1f, qf[1], s, 0, 0, 0);
      s = __builtin_amdgcn_mfma_f32_16x16x32_bf16(k2f, qf[2], s, 0, 0, 0);
      st[t2] = s;
    }
    float tmax = -1e30f;
#pragma unroll
    for (int t2 = 0; t2 < 4; ++t2)
#pragma unroll
      for (int r = 0; r < 4; ++r) tmax = fmaxf(tmax, st[t2][r]);
    tmax = fmaxf(tmax, __shfl_xor(tmax, 16));
    tmax = fmaxf(tmax, __shfl_xor(tmax, 32));
    tmax *= sc;
    const float m_new = fmaxf(m_run, tmax);
    const float alpha = exp2f(m_run - m_new);
    float tsum = 0.f;
#pragma unroll
    for (int t2 = 0; t2 < 4; ++t2) {
      bf16x4 pb;
#pragma unroll
      for (int r = 0; r < 4; ++r) {
        const float p = exp2f(st[t2][r] * sc - m_new);
        tsum += p;
        pb[r] = (__bf16)p;
      }
      *(bf16x4*)&Pl[w][lq * 72 + t2 * 16 + lg * 4] = pb;
    }
    tsum += __shfl_xor(tsum, 16);
    tsum += __shfl_xor(tsum, 32);
    l_run = l_run * alpha + tsum;
    m_run = m_new;
    float al[4];
#pragma unroll
    for (int r = 0; r < 4; ++r) al[r] = __shfl(alpha, lg * 4 + r);
#pragma unroll
    for (int ni = 0; ni < 6; ++ni)
#pragma unroll
      for (int r = 0; r < 4; ++r) o[ni][r] *= al[r];
#pragma unroll
    for (int ks = 0; ks < 2; ++ks) {
      bf16x8 pa = *(const bf16x8*)&Pl[w][lq * 72 + ks * 32 + lg * 8];
#pragma unroll
      for (int ni = 0; ni < 6; ++ni) {
        bf16x8 vf = *(const bf16x8*)&Vt[(ni * 16 + lq) * 72 + ks * 32 + lg * 8];
        o[ni] = __builtin_amdgcn_mfma_f32_16x16x32_bf16(pa, vf, o[ni], 0, 0, 0);
      }
    }
  }
  float linv[4];
#pragma unroll
  for (int r = 0; r < 4; ++r) linv[r] = 1.f / __shfl(l_run, lg * 4 + r);
#pragma unroll
  for (int ni = 0; ni < 6; ++ni)
#pragma unroll
    for (int r = 0; r < 4; ++r) {
      const int gq = qt * 64 + w * 16 + lg * 4 + r;
      const int d = ni * 16 + lq;
      ao[(size_t)(gq * 16 + bp) * DIM + h * HD + d] = (__bf16)(o[ni][r] * linv[r]);
    }
}

extern "C" void kernel_launch(void* const* d_in, const int* in_sizes, int n_in,
                              void* d_out, int out_size, void* d_ws, size_t ws_size,
                              hipStream_t stream) {
  const float* hs = (const float*)d_in[0];
  const float* wq = (const float*)d_in[1];
  const float* bq = (const float*)d_in[2];
  const float* wk = (const float*)d_in[3];
  const float* bk = (const float*)d_in[4];
  const float* wv = (const float*)d_in[5];
  const float* bv = (const float*)d_in[6];
  const float* wo = (const float*)d_in[7];
  const float* bo = (const float*)d_in[8];
  float* out = (float*)d_out;

  char* ws = (char*)d_ws;
  __bf16* wqkvT = (__bf16*)(ws);                               // 31,850,496
  __bf16* woT   = (__bf16*)(ws + 31850496);                    // 10,616,832
  __bf16* hsb   = (__bf16*)(ws + 42467328);                    // 37,748,736
  __bf16* qb    = (__bf16*)(ws + 80216064);                    // 37,748,736
  __bf16* kbuf  = (__bf16*)(ws + 117964800);                   // 37,748,736
  __bf16* vbuf  = (__bf16*)(ws + 155713536);                   // 37,748,736
  __bf16* ao    = hsb;  // reuse: hs_bf16 dead after gemm_qkv

  pack_w_kernel<<<dim3(36, 36, 4), 256, 0, stream>>>(wq, wk, wv, wo, wqkvT, woT);
  pack_hs_kernel<<<18432, 256, 0, stream>>>((const float4*)hs, (bf16x4*)hsb);
  gemm8p_kernel<0><<<864, 512, 0, stream>>>(hsb, wqkvT, bq, bk, bv, qb, kbuf, vbuf, nullptr);
  attn_kernel<<<3072, 256, 0, stream>>>(qb, kbuf, vbuf, ao);
  gemm8p_kernel<1><<<576, 512, 0, stream>>>(ao, woT, bo, nullptr, nullptr, nullptr, nullptr, nullptr, out);
}